// Round 20
// baseline (38.187 us; speedup 1.0000x reference)
//
#include <hip/hip_runtime.h>

// RejectionSampler: B=128 requests, S=8 draft tokens each, V=32000 vocab.
// SINGLE dispatch, ZERO workspace, ZERO cross-block communication.
// (R18/R19 showed any cross-block coordination on the walk's critical path
// costs as much as its parallelism buys; this keeps R17's structure.)
//
// One block per request (128 blocks x 1024 thr) walking its 8 tokens
// sequentially with a TWO-deep speculative row prefetch (bufA/bufB, fully
// unrolled -> compile-time indexing). NEW vs R17: rcp(q) for the whole
// request is prefetched into 32 registers during the prime phase -- q is
// per-REQUEST, needed by ~90% of blocks, and its 128 KB fetch + rcp ops
// fully overlap the walk. The argmax phase then streams only d from HBM
// (l row is L2-hot from the walk), halving the tail's HBM traffic.
//
// Per-step: consume buffer (exp2-accumulate), reissue it for row p+2,
// butterfly-reduce, ONE barrier (s_red parity double-buffer; every thread
// redundantly sums the 16 partials in fixed order -> bit-identical D ->
// uniform decision without a second barrier).
//
// Division-free, max-free math (positive rescalings preserve decisions):
//   e = exp2(l * log2e/temp);  accept: e_t >= u*d_t*D, D = sum e
//   argmax((e/D - d)/q) == argmax(e*rcp(q) - D*(d*rcp(q)))
// The SAME D value (fixed reduction order) feeds accept and argmax.

constexpr int PLACEHOLDER = -1;
constexpr int B = 128;
constexpr int S = 8;
constexpr int V = 32000;
constexpr int NV4 = V / 4;            // 8000 float4 per row

extern "C" __device__ float __builtin_amdgcn_exp2f(float);
extern "C" __device__ float __builtin_amdgcn_rcpf(float);

__global__ __launch_bounds__(1024, 4)   // 16-wave block => VGPR cap 128
void rs_seq(const float* __restrict__ logits,
            const float* __restrict__ dprobs,
            const float* __restrict__ q,
            const int*   __restrict__ draft_ids,
            const int*   __restrict__ bonus_ids,
            const float* __restrict__ temperature,
            const float* __restrict__ uniform_probs,
            int* __restrict__ out)
{
    const int b   = blockIdx.x;                  // one block per request
    const int tid = threadIdx.x, lane = tid & 63, wid = tid >> 6; // 16 waves
    __shared__ float s_redA[16], s_redB[16];
    __shared__ float s_ld[S], s_dd[S], s_u[S];
    __shared__ int   s_dt[S];
    __shared__ int   s_bonus;
    __shared__ float s_val[16];
    __shared__ int   s_idx[16];

    const float c = 1.4426950408889634f / temperature[b];

    // ---- block-start scalar prefetch: all 8 tokens' accept-test scalars ----
    if (wid == 0) {
        if (lane < S) {
            const int t  = b * S + lane;
            const int dt = draft_ids[t];
            s_dt[lane] = dt;
            s_u[lane]  = uniform_probs[t];
            s_ld[lane] = logits[(size_t)t * V + dt];
            s_dd[lane] = dprobs[(size_t)t * V + dt];
        }
        if (lane == 8) s_bonus = bonus_ids[b];
    }

    const float4* lbase = (const float4*)(logits + (size_t)(b * S) * V);
    const float4* qrow  = (const float4*)(q      + (size_t)b * V);

    // ---- prime: row 0 -> bufA, row 1 -> bufB, request q row -> rqv (regs),
    // converted to reciprocals in place (overlaps the walk) ----
    float4 bufA[8], bufB[8], rqv[8];
    #pragma unroll
    for (int j = 0; j < 8; ++j) {
        const int i4 = j * 1024 + tid;
        if (i4 < NV4) bufA[j] = lbase[i4];
    }
    #pragma unroll
    for (int j = 0; j < 8; ++j) {
        const int i4 = j * 1024 + tid;
        if (i4 < NV4) bufB[j] = lbase[NV4 + i4];
    }
    #pragma unroll
    for (int j = 0; j < 8; ++j) {
        const int i4 = j * 1024 + tid;
        if (i4 < NV4) rqv[j] = qrow[i4];
    }
    #pragma unroll
    for (int j = 0; j < 8; ++j) {
        const int i4 = j * 1024 + tid;
        if (i4 < NV4) {
            rqv[j].x = __builtin_amdgcn_rcpf(rqv[j].x);
            rqv[j].y = __builtin_amdgcn_rcpf(rqv[j].y);
            rqv[j].z = __builtin_amdgcn_rcpf(rqv[j].z);
            rqv[j].w = __builtin_amdgcn_rcpf(rqv[j].w);
        }
    }

    int   need_p = S;
    float Dsave  = 0.f;

    // step P: consume BUF (holds row P), reissue BUF for row P+2, reduce via
    // SRED (parity double-buffer), all-thread redundant D -> uniform decision
#define WALK_STEP(P, BUF, SRED)                                             \
    {                                                                       \
        float lsum = 0.f;                                                   \
        _Pragma("unroll")                                                   \
        for (int j = 0; j < 8; ++j) {                                       \
            const int i4 = j * 1024 + tid;                                  \
            if (i4 < NV4) {                                                 \
                const float4 v = BUF[j];                                    \
                lsum += (__builtin_amdgcn_exp2f(v.x * c) +                  \
                         __builtin_amdgcn_exp2f(v.y * c)) +                 \
                        (__builtin_amdgcn_exp2f(v.z * c) +                  \
                         __builtin_amdgcn_exp2f(v.w * c));                  \
            }                                                               \
        }                                                                   \
        if ((P) + 2 < S) {                                                  \
            _Pragma("unroll")                                               \
            for (int j = 0; j < 8; ++j) {                                   \
                const int i4 = j * 1024 + tid;                              \
                if (i4 < NV4) BUF[j] = lbase[((P) + 2) * NV4 + i4];         \
            }                                                               \
        }                                                                   \
        _Pragma("unroll")                                                   \
        for (int off = 32; off >= 1; off >>= 1)                             \
            lsum += __shfl_xor(lsum, off, 64);                              \
        if (lane == 0) SRED[wid] = lsum;                                    \
        __syncthreads();                                                    \
        float D = 0.f;                                                      \
        _Pragma("unroll")                                                   \
        for (int w = 0; w < 16; ++w) D += SRED[w];                          \
        const float e_d = __builtin_amdgcn_exp2f(s_ld[(P)] * c);            \
        const bool dec = (s_dd[(P)] > 0.f) &&                               \
                         (e_d >= s_u[(P)] * s_dd[(P)] * D);                 \
        if (!dec) { need_p = (P); Dsave = D; goto walk_done; }              \
    }

    WALK_STEP(0, bufA, s_redA)
    WALK_STEP(1, bufB, s_redB)
    WALK_STEP(2, bufA, s_redA)
    WALK_STEP(3, bufB, s_redB)
    WALK_STEP(4, bufA, s_redA)
    WALK_STEP(5, bufB, s_redB)
    WALK_STEP(6, bufA, s_redA)
    WALK_STEP(7, bufB, s_redB)
#undef WALK_STEP

walk_done:
    // ---- all accepted: trivial row ----
    if (need_p >= S) {
        if (tid < S) out[b * (S + 1) + tid] = s_dt[tid];
        if (tid == 0) out[b * (S + 1) + S] = s_bonus;
        return;
    }

    // ---- residual argmax for the rejected token ----
    // l row: L2-hot (this block streamed it); q: in registers; d: HBM stream.
    {
        const int   t = b * S + need_p;
        const float D = Dsave;
        const float4* lrow = (const float4*)(logits + (size_t)t * V);
        const float4* drow = (const float4*)(dprobs + (size_t)t * V);

        float bestv = -__builtin_inff();
        int   besti = 0x7fffffff;

#define RS_COMP(LC, DC, RQ, GIDX)                                          \
        {                                                                  \
            const float e = __builtin_amdgcn_exp2f((LC) * c);              \
            const float r = fmaf(-((DC) * (RQ)), D, e * (RQ));             \
            if (r > bestv) { bestv = r; besti = (GIDX); }                  \
        }

        // 2 phases x (4+4) batched float4 loads; q comes from registers
        #pragma unroll
        for (int ph = 0; ph < 2; ++ph) {
            float4 lv[4], dv[4];
            #pragma unroll
            for (int j = 0; j < 4; ++j) {
                const int i4 = (ph * 4 + j) * 1024 + tid;
                if (i4 < NV4) lv[j] = lrow[i4];
            }
            #pragma unroll
            for (int j = 0; j < 4; ++j) {
                const int i4 = (ph * 4 + j) * 1024 + tid;
                if (i4 < NV4) dv[j] = drow[i4];
            }
            #pragma unroll
            for (int j = 0; j < 4; ++j) {
                const int jj = ph * 4 + j;
                const int i4 = jj * 1024 + tid;
                if (i4 < NV4) {
                    const int base = i4 * 4;
                    RS_COMP(lv[j].x, dv[j].x, rqv[jj].x, base + 0)
                    RS_COMP(lv[j].y, dv[j].y, rqv[jj].y, base + 1)
                    RS_COMP(lv[j].z, dv[j].z, rqv[jj].z, base + 2)
                    RS_COMP(lv[j].w, dv[j].w, rqv[jj].w, base + 3)
                }
            }
        }
#undef RS_COMP

        // wave butterfly then wave-0 cross-wave reduce (min-index ties)
        #pragma unroll
        for (int off = 32; off >= 1; off >>= 1) {
            const float ov = __shfl_xor(bestv, off, 64);
            const int   oi = __shfl_xor(besti, off, 64);
            if (ov > bestv || (ov == bestv && oi < besti)) { bestv = ov; besti = oi; }
        }
        if (lane == 0) { s_val[wid] = bestv; s_idx[wid] = besti; }
        __syncthreads();
        if (wid == 0) {
            float bv = (lane < 16) ? s_val[lane] : -__builtin_inff();
            int   bi = (lane < 16) ? s_idx[lane] : 0x7fffffff;
            #pragma unroll
            for (int off = 8; off >= 1; off >>= 1) {
                const float ov = __shfl_xor(bv, off, 64);
                const int   oi = __shfl_xor(bi, off, 64);
                if (ov > bv || (ov == bv && oi < bi)) { bv = ov; bi = oi; }
            }
            if (lane == 0) {
                #pragma unroll
                for (int p = 0; p < S; ++p) {
                    int tok = PLACEHOLDER;
                    if (p < need_p)       tok = s_dt[p];
                    else if (p == need_p) tok = bi;
                    out[b * (S + 1) + p] = tok;
                }
                out[b * (S + 1) + S] = PLACEHOLDER;   // rejection => no bonus
            }
        }
    }
}

extern "C" void kernel_launch(void* const* d_in, const int* in_sizes, int n_in,
                              void* d_out, int out_size, void* d_ws, size_t ws_size,
                              hipStream_t stream) {
    const float* logits      = (const float*)d_in[0];
    const float* dprobs      = (const float*)d_in[1];
    const int*   draft_ids   = (const int*)d_in[2];
    const int*   bonus_ids   = (const int*)d_in[3];
    const float* temperature = (const float*)d_in[4];
    const float* uniform     = (const float*)d_in[5];
    const float* q           = (const float*)d_in[6];
    // d_in[7] cu_num_draft_tokens unused (uniform S per request)

    int* out = (int*)d_out;
    rs_seq<<<B, 1024, 0, stream>>>(logits, dprobs, q, draft_ids, bonus_ids,
                                   temperature, uniform, out);
}

// Round 21
// 30.639 us; speedup vs baseline: 1.2463x; 1.2463x over previous
//
#include <hip/hip_runtime.h>

// RejectionSampler: B=128 requests, S=8 draft tokens each, V=32000 vocab.
// SINGLE dispatch, ZERO workspace, ZERO cross-block communication.
// == R17 kernel, the session best (30.6 us). R18-R20 variants all regressed:
//    cross-block walk coordination costs >= its parallelism gain (R18/R19),
//    and a 3rd register-resident row buffer spills past the 128-VGPR cap
//    (R20). This structure is ~8% above the data-movement + straggler floor.
//
// One block per request (128 blocks x 1024 thr) walking its 8 tokens
// sequentially with a TWO-deep speculative row prefetch (bufA/bufB rotation,
// fully unrolled -> all buffer indexing compile-time). The rejected token's
// row is re-read from L2 during the argmax (this block just streamed it;
// 128 KB << 4 MB/XCD) instead of being held in registers -- that VGPR
// headroom is what pays for the 2-deep prefetch.
//
// Per-step: consume buffer (exp2-accumulate), reissue it for row p+2,
// butterfly-reduce, ONE barrier (s_red double-buffered by parity; every
// thread then redundantly sums the 16 partials in a fixed order ->
// bit-identical D on all threads -> uniform accept decision, no second
// barrier needed; next step writes the OTHER s_red array so no WAR).
//
// Division-free, max-free math (positive rescalings preserve decisions):
//   e = exp2(l * log2e/temp);  accept: e_t >= u*d_t*D, D = sum e
//   argmax((e/D - d)/q) == argmax(e*rcp(q) - D*(d*rcp(q)))
// The SAME D value (fixed reduction order) feeds accept and argmax.

constexpr int PLACEHOLDER = -1;
constexpr int B = 128;
constexpr int S = 8;
constexpr int V = 32000;
constexpr int NV4 = V / 4;            // 8000 float4 per row

extern "C" __device__ float __builtin_amdgcn_exp2f(float);
extern "C" __device__ float __builtin_amdgcn_rcpf(float);

__global__ __launch_bounds__(1024, 4)   // 16-wave block => VGPR cap 128
void rs_seq(const float* __restrict__ logits,
            const float* __restrict__ dprobs,
            const float* __restrict__ q,
            const int*   __restrict__ draft_ids,
            const int*   __restrict__ bonus_ids,
            const float* __restrict__ temperature,
            const float* __restrict__ uniform_probs,
            int* __restrict__ out)
{
    const int b   = blockIdx.x;                  // one block per request
    const int tid = threadIdx.x, lane = tid & 63, wid = tid >> 6; // 16 waves
    __shared__ float s_redA[16], s_redB[16];
    __shared__ float s_ld[S], s_dd[S], s_u[S];
    __shared__ int   s_dt[S];
    __shared__ int   s_bonus;
    __shared__ float s_val[16];
    __shared__ int   s_idx[16];

    const float c = 1.4426950408889634f / temperature[b];

    // ---- block-start scalar prefetch: all 8 tokens' accept-test scalars ----
    if (wid == 0) {
        if (lane < S) {
            const int t  = b * S + lane;
            const int dt = draft_ids[t];
            s_dt[lane] = dt;
            s_u[lane]  = uniform_probs[t];
            s_ld[lane] = logits[(size_t)t * V + dt];
            s_dd[lane] = dprobs[(size_t)t * V + dt];
        }
        if (lane == 8) s_bonus = bonus_ids[b];
    }

    const float4* lbase = (const float4*)(logits + (size_t)(b * S) * V);

    // ---- prime the 2-deep pipeline: row 0 -> bufA, row 1 -> bufB ----
    float4 bufA[8], bufB[8];
    #pragma unroll
    for (int j = 0; j < 8; ++j) {
        const int i4 = j * 1024 + tid;
        if (i4 < NV4) bufA[j] = lbase[i4];
    }
    #pragma unroll
    for (int j = 0; j < 8; ++j) {
        const int i4 = j * 1024 + tid;
        if (i4 < NV4) bufB[j] = lbase[NV4 + i4];
    }

    int   need_p = S;
    float Dsave  = 0.f;

    // step P: consume BUF (holds row P), reissue BUF for row P+2, reduce via
    // SRED (parity double-buffer), all-thread redundant D -> uniform decision
#define WALK_STEP(P, BUF, SRED)                                             \
    {                                                                       \
        float lsum = 0.f;                                                   \
        _Pragma("unroll")                                                   \
        for (int j = 0; j < 8; ++j) {                                       \
            const int i4 = j * 1024 + tid;                                  \
            if (i4 < NV4) {                                                 \
                const float4 v = BUF[j];                                    \
                lsum += (__builtin_amdgcn_exp2f(v.x * c) +                  \
                         __builtin_amdgcn_exp2f(v.y * c)) +                 \
                        (__builtin_amdgcn_exp2f(v.z * c) +                  \
                         __builtin_amdgcn_exp2f(v.w * c));                  \
            }                                                               \
        }                                                                   \
        if ((P) + 2 < S) {                                                  \
            _Pragma("unroll")                                               \
            for (int j = 0; j < 8; ++j) {                                   \
                const int i4 = j * 1024 + tid;                              \
                if (i4 < NV4) BUF[j] = lbase[((P) + 2) * NV4 + i4];         \
            }                                                               \
        }                                                                   \
        _Pragma("unroll")                                                   \
        for (int off = 32; off >= 1; off >>= 1)                             \
            lsum += __shfl_xor(lsum, off, 64);                              \
        if (lane == 0) SRED[wid] = lsum;                                    \
        __syncthreads();                                                    \
        float D = 0.f;                                                      \
        _Pragma("unroll")                                                   \
        for (int w = 0; w < 16; ++w) D += SRED[w];                          \
        const float e_d = __builtin_amdgcn_exp2f(s_ld[(P)] * c);            \
        const bool dec = (s_dd[(P)] > 0.f) &&                               \
                         (e_d >= s_u[(P)] * s_dd[(P)] * D);                 \
        if (!dec) { need_p = (P); Dsave = D; goto walk_done; }              \
    }

    WALK_STEP(0, bufA, s_redA)
    WALK_STEP(1, bufB, s_redB)
    WALK_STEP(2, bufA, s_redA)
    WALK_STEP(3, bufB, s_redB)
    WALK_STEP(4, bufA, s_redA)
    WALK_STEP(5, bufB, s_redB)
    WALK_STEP(6, bufA, s_redA)
    WALK_STEP(7, bufB, s_redB)
#undef WALK_STEP

walk_done:
    // ---- all accepted: trivial row ----
    if (need_p >= S) {
        if (tid < S) out[b * (S + 1) + tid] = s_dt[tid];
        if (tid == 0) out[b * (S + 1) + S] = s_bonus;
        return;
    }

    // ---- residual argmax for the rejected token ----
    // l row: L2-hot (this block streamed it moments ago); d,q: HBM stream.
    {
        const int   t = b * S + need_p;
        const float D = Dsave;
        const float4* lrow = (const float4*)(logits + (size_t)t * V);
        const float4* drow = (const float4*)(dprobs + (size_t)t * V);
        const float4* qrow = (const float4*)(q      + (size_t)b * V);

        float bestv = -__builtin_inff();
        int   besti = 0x7fffffff;

#define RS_COMP(LC, DC, QC, GIDX)                                          \
        {                                                                  \
            const float e  = __builtin_amdgcn_exp2f((LC) * c);             \
            const float rq = __builtin_amdgcn_rcpf(QC);                    \
            const float r  = fmaf(-((DC) * rq), D, e * rq);                \
            if (r > bestv) { bestv = r; besti = (GIDX); }                  \
        }

        // 2 phases x (4+4+4) batched float4 loads: bounded VGPR, good MLP
        #pragma unroll
        for (int ph = 0; ph < 2; ++ph) {
            float4 lv[4], dv[4], qv[4];
            #pragma unroll
            for (int j = 0; j < 4; ++j) {
                const int i4 = (ph * 4 + j) * 1024 + tid;
                if (i4 < NV4) lv[j] = lrow[i4];
            }
            #pragma unroll
            for (int j = 0; j < 4; ++j) {
                const int i4 = (ph * 4 + j) * 1024 + tid;
                if (i4 < NV4) dv[j] = drow[i4];
            }
            #pragma unroll
            for (int j = 0; j < 4; ++j) {
                const int i4 = (ph * 4 + j) * 1024 + tid;
                if (i4 < NV4) qv[j] = qrow[i4];
            }
            #pragma unroll
            for (int j = 0; j < 4; ++j) {
                const int i4 = (ph * 4 + j) * 1024 + tid;
                if (i4 < NV4) {
                    const int base = i4 * 4;
                    RS_COMP(lv[j].x, dv[j].x, qv[j].x, base + 0)
                    RS_COMP(lv[j].y, dv[j].y, qv[j].y, base + 1)
                    RS_COMP(lv[j].z, dv[j].z, qv[j].z, base + 2)
                    RS_COMP(lv[j].w, dv[j].w, qv[j].w, base + 3)
                }
            }
        }
#undef RS_COMP

        // wave butterfly then wave-0 cross-wave reduce (min-index ties)
        #pragma unroll
        for (int off = 32; off >= 1; off >>= 1) {
            const float ov = __shfl_xor(bestv, off, 64);
            const int   oi = __shfl_xor(besti, off, 64);
            if (ov > bestv || (ov == bestv && oi < besti)) { bestv = ov; besti = oi; }
        }
        if (lane == 0) { s_val[wid] = bestv; s_idx[wid] = besti; }
        __syncthreads();
        if (wid == 0) {
            float bv = (lane < 16) ? s_val[lane] : -__builtin_inff();
            int   bi = (lane < 16) ? s_idx[lane] : 0x7fffffff;
            #pragma unroll
            for (int off = 8; off >= 1; off >>= 1) {
                const float ov = __shfl_xor(bv, off, 64);
                const int   oi = __shfl_xor(bi, off, 64);
                if (ov > bv || (ov == bv && oi < bi)) { bv = ov; bi = oi; }
            }
            if (lane == 0) {
                #pragma unroll
                for (int p = 0; p < S; ++p) {
                    int tok = PLACEHOLDER;
                    if (p < need_p)       tok = s_dt[p];
                    else if (p == need_p) tok = bi;
                    out[b * (S + 1) + p] = tok;
                }
                out[b * (S + 1) + S] = PLACEHOLDER;   // rejection => no bonus
            }
        }
    }
}

extern "C" void kernel_launch(void* const* d_in, const int* in_sizes, int n_in,
                              void* d_out, int out_size, void* d_ws, size_t ws_size,
                              hipStream_t stream) {
    const float* logits      = (const float*)d_in[0];
    const float* dprobs      = (const float*)d_in[1];
    const int*   draft_ids   = (const int*)d_in[2];
    const int*   bonus_ids   = (const int*)d_in[3];
    const float* temperature = (const float*)d_in[4];
    const float* uniform     = (const float*)d_in[5];
    const float* q           = (const float*)d_in[6];
    // d_in[7] cu_num_draft_tokens unused (uniform S per request)

    int* out = (int*)d_out;
    rs_seq<<<B, 1024, 0, stream>>>(logits, dprobs, q, draft_ids, bonus_ids,
                                   temperature, uniform, out);
}